// Round 12
// baseline (290.754 us; speedup 1.0000x reference)
//
#include <hip/hip_runtime.h>
#include <hip/hip_bf16.h>
#include <math.h>

#define B_ROWS 8192
#define D_INK  1024
#define D_H    512
#define N_E    8
#define OUT_D  1024
#define LN_EPS 1e-5f
#define GAP_TAU 3e-3f

typedef _Float16 f16x8 __attribute__((ext_vector_type(8)));
typedef _Float16 f16x4v __attribute__((ext_vector_type(4)));
typedef float    f32x4  __attribute__((ext_vector_type(4)));

#define GLOBAL_AS __attribute__((address_space(1)))
#define LDS_AS    __attribute__((address_space(3)))

// Async 16B global->LDS DMA. LDS dest is wave-uniform base + lane*16.
__device__ __forceinline__ void async16(const void* gptr, void* lptr) {
  __builtin_amdgcn_global_load_lds((const GLOBAL_AS unsigned int*)gptr,
                                   (LDS_AS unsigned int*)lptr, 16, 0, 0);
}

__device__ __forceinline__ float gelu_exact(float x) {
  return 0.5f * x * (1.0f + erff(x * 0.707106781186547524f));
}
__device__ __forceinline__ float clamp_diag(float v) {
  return fminf(fmaxf(v, -1e15f), 1e15f);
}

// ---- fused prep: convert x -> fp16, transpose w1 and We -> fp16, zero
// counts. One kernel instead of 4 dispatch nodes. Roles by blockIdx range.
__global__ __launch_bounds__(256) void prep_kernel(
    const float* __restrict__ x, f16x4v* __restrict__ x16h4,
    const float* __restrict__ gate_w1, _Float16* __restrict__ w1th,
    const float* __restrict__ We, _Float16* __restrict__ wet,
    int* __restrict__ counts) {
  __shared__ float tile[32][33];
  int bid = blockIdx.x, tid = threadIdx.x;
  if (bid < 8192) {  // convert role: 8192 blocks cover 8192x1024 / 4
    if (bid == 0 && tid < 16) counts[tid] = 0;  // counts[8] + nflag + pad
    int i = bid * 256 + tid;
    float4 v = ((const float4*)x)[i];
    f16x4v h;
    h[0] = (_Float16)v.x; h[1] = (_Float16)v.y;
    h[2] = (_Float16)v.z; h[3] = (_Float16)v.w;
    x16h4[i] = h;
    return;
  }
  const float* src; _Float16* dst; int C; long base; int c0, r0;
  if (bid < 8192 + 512) {  // w1 transpose: 16 x 32 tiles
    int b2 = bid - 8192;
    src = gate_w1; dst = w1th; C = D_H; base = 0;
    c0 = (b2 & 15) * 32; r0 = (b2 >> 4) * 32;
  } else {  // We transpose: 32 x 32 x 8 tiles
    int b3 = bid - 8704;
    src = We; dst = wet; C = OUT_D;
    int zx = b3 & 31, zy = (b3 >> 5) & 31, zz = b3 >> 10;
    base = (long)zz * D_INK * OUT_D;
    c0 = zx * 32; r0 = zy * 32;
  }
  int tx = tid & 31, ty = tid >> 5;
#pragma unroll
  for (int i = ty; i < 32; i += 8)
    tile[i][tx] = src[base + (long)(r0 + i) * C + (c0 + tx)];
  __syncthreads();
#pragma unroll
  for (int i = ty; i < 32; i += 8)
    dst[base + (long)(c0 + i) * D_INK + (r0 + tx)] = (_Float16)tile[tx][i];
}

// LDS tile layout (both GEMMs): rows of 64 fp16 = 8 segs of 16B, segment
// index XOR-swizzled by (row&7): data(row,seg) at row*128 + (seg^(row&7))*16.
// Staging fetches global segment slot^(row&7) into LDS slot `slot` so the
// DMA's rigid base+lane*16 mapping lands data swizzled. MFMA reads then are
// 2-way bank-aliased (free, m136) instead of 16-way.
//
// Structure law (rounds 0-4, 10-11): single-buffer 2-barrier K-loop with
// >=4 blocks/CU wins. EVERY <4 blocks/CU variant regressed, including the
// r11 2-way dispatch split (2 blocks/CU per half: 47.5x2 = 95us vs 71.5).
// Grid-mapping law (rounds 7-8): keep the STREAMING operand (B) L2-pinned
// per XCD (nt fastest); let the gathered operand (A) refetch through L3.
// Latency law (rounds 6/10): sparse-grid kernels (~1 block/CU) expose full
// miss latency on every dependent load batch — wall time = iters x latency;
// fix by batching MORE loads per wait (deeper MLP), not more blocks.

// Stage one 128x64 A-tile + 128x64 B-tile K-step into the given LDS buffers.
__device__ __forceinline__ void stage8(const char* const (&ap)[4],
                                       const char* const (&bp)[4], long koff,
                                       char* Ab, char* Bb, int wave) {
#pragma unroll
  for (int i = 0; i < 4; ++i) {
    async16(ap[i] + koff, Ab + (i * 256 + wave * 64) * 16);
    async16(bp[i] + koff, Bb + (i * 256 + wave * 64) * 16);
  }
}

// One K-step (BK=64) of 16x16x32 MFMAs from swizzled LDS tiles. 32 MFMA/wave.
__device__ __forceinline__ void tile_compute(const char* Ab, const char* Bb,
                                             int wm, int wn, int cl, int quad,
                                             f32x4 (&acc)[4][4]) {
#pragma unroll
  for (int ks = 0; ks < 2; ++ks) {
    f16x8 ah[4], bh[4];
#pragma unroll
    for (int mi = 0; mi < 4; ++mi) {
      int row = wm * 64 + mi * 16 + cl;
      ah[mi] = *(const f16x8*)(Ab + row * 128 + (((ks * 4 + quad) ^ (cl & 7)) * 16));
    }
#pragma unroll
    for (int ni = 0; ni < 4; ++ni) {
      int row = wn * 64 + ni * 16 + cl;
      bh[ni] = *(const f16x8*)(Bb + row * 128 + (((ks * 4 + quad) ^ (cl & 7)) * 16));
    }
#pragma unroll
    for (int mi = 0; mi < 4; ++mi)
#pragma unroll
      for (int ni = 0; ni < 4; ++ni)
        acc[mi][ni] = __builtin_amdgcn_mfma_f32_16x16x32_f16(ah[mi], bh[ni], acc[mi][ni], 0, 0, 0);
  }
}

// ---- gate GEMM, fp16 1-term: g = gelu(x@W1 + b1) fp32 out ----
// 64x64 tile -> 1024 blocks = 4 blocks/CU; nt fastest (B-slice L2-pinned).
__global__ __launch_bounds__(256) void gate_gemm_kernel(
    const _Float16* __restrict__ xh, const _Float16* __restrict__ wh,
    const float* __restrict__ b1, float* __restrict__ g) {
  __shared__ __align__(16) unsigned short Ah[64 * 64];
  __shared__ __align__(16) unsigned short Bh[64 * 64];
  int tid = threadIdx.x, lane = tid & 63, wave = tid >> 6;
  int wm = wave >> 1, wn = wave & 1;
  int n0 = blockIdx.x * 64, m0 = blockIdx.y * 64;

  const char* pah[2]; const char* pbh[2];
#pragma unroll
  for (int i = 0; i < 2; ++i) {
    int f = i * 256 + tid;
    int rowt = f >> 3, slot = f & 7;
    int seg = slot ^ (rowt & 7);  // source-address swizzle
    pah[i] = (const char*)xh + (long)(m0 + rowt) * (D_INK * 2) + seg * 16;
    pbh[i] = (const char*)wh + (long)(n0 + rowt) * (D_INK * 2) + seg * 16;
  }
  f32x4 acc[2][2];
#pragma unroll
  for (int mi = 0; mi < 2; ++mi)
#pragma unroll
    for (int ni = 0; ni < 2; ++ni) acc[mi][ni] = (f32x4){0.f, 0.f, 0.f, 0.f};

  int cl = lane & 15, quad = lane >> 4;
  for (int k0 = 0; k0 < D_INK; k0 += 64) {
    long koff = (long)k0 * 2;
#pragma unroll
    for (int i = 0; i < 2; ++i) {
      async16(pah[i] + koff, (char*)Ah + (i * 256 + wave * 64) * 16);
      async16(pbh[i] + koff, (char*)Bh + (i * 256 + wave * 64) * 16);
    }
    __syncthreads();  // drains DMA (vmcnt) -> tile visible
#pragma unroll
    for (int ks = 0; ks < 2; ++ks) {
      f16x8 ah[2], bh[2];
#pragma unroll
      for (int mi = 0; mi < 2; ++mi) {
        int row = wm * 32 + mi * 16 + cl;
        ah[mi] = *(const f16x8*)((const char*)Ah + row * 128 +
                                 (((ks * 4 + quad) ^ (cl & 7)) * 16));
      }
#pragma unroll
      for (int ni = 0; ni < 2; ++ni) {
        int row = wn * 32 + ni * 16 + cl;
        bh[ni] = *(const f16x8*)((const char*)Bh + row * 128 +
                                 (((ks * 4 + quad) ^ (cl & 7)) * 16));
      }
#pragma unroll
      for (int mi = 0; mi < 2; ++mi)
#pragma unroll
        for (int ni = 0; ni < 2; ++ni)
          acc[mi][ni] = __builtin_amdgcn_mfma_f32_16x16x32_f16(ah[mi], bh[ni], acc[mi][ni], 0, 0, 0);
    }
    __syncthreads();  // tile consumed before next DMA overwrites
  }
#pragma unroll
  for (int mi = 0; mi < 2; ++mi)
#pragma unroll
    for (int r = 0; r < 4; ++r) {
      int row = m0 + wm * 32 + mi * 16 + quad * 4 + r;
#pragma unroll
      for (int ni = 0; ni < 2; ++ni) {
        int col = n0 + wn * 32 + ni * 16 + cl;
        float v = clamp_diag(acc[mi][ni][r] + b1[col]);
        g[(long)row * D_H + col] = gelu_exact(v);
      }
    }
}

// ---- Phase A: scores (fp32) + flag close 2nd/3rd gaps. One wave per row.
// w2 slice per lane (256B contiguous) preloaded as 16 float4s; FMA order
// identical to original (bitwise-same fp32 result).
__global__ __launch_bounds__(256) void score_kernel(
    const float* __restrict__ g, const float* __restrict__ w2,
    const float* __restrict__ b2, float* __restrict__ scores,
    int* __restrict__ nflag, int* __restrict__ worklist) {
  int tid = threadIdx.x, lane = tid & 63, wave = tid >> 6;
  int b = blockIdx.x * 4 + wave;
  const float* grow = g + (long)b * D_H + lane * 8;
  float4 g0 = *(const float4*)grow;
  float4 g1 = *(const float4*)(grow + 4);
  float gv[8] = {g0.x, g0.y, g0.z, g0.w, g1.x, g1.y, g1.z, g1.w};
  float4 wv4[16];
  const float4* wq = (const float4*)(w2 + lane * 64);
#pragma unroll
  for (int jj = 0; jj < 16; ++jj) wv4[jj] = wq[jj];
  const float* wv = (const float*)wv4;  // wv[j*8+e] = w2[(lane*8+j)*8+e]
  float acc[8];
#pragma unroll
  for (int e = 0; e < 8; ++e) acc[e] = 0.f;
#pragma unroll
  for (int j = 0; j < 8; ++j)
#pragma unroll
    for (int e = 0; e < 8; ++e) acc[e] += gv[j] * wv[j * 8 + e];
#pragma unroll
  for (int off = 32; off >= 1; off >>= 1)
#pragma unroll
    for (int e = 0; e < 8; ++e) acc[e] += __shfl_xor(acc[e], off, 64);
  if (lane == 0) {
    float s[8];
#pragma unroll
    for (int e = 0; e < 8; ++e) { s[e] = acc[e] + b2[e]; scores[b * N_E + e] = s[e]; }
    int i0 = 0;
#pragma unroll
    for (int e = 1; e < 8; ++e) if (s[e] > s[i0]) i0 = e;
    int i1 = (i0 == 0) ? 1 : 0;
#pragma unroll
    for (int e = 0; e < 8; ++e) if (e != i0 && s[e] > s[i1]) i1 = e;
    float s2 = -3e38f;
#pragma unroll
    for (int e = 0; e < 8; ++e) if (e != i0 && e != i1 && s[e] > s2) s2 = s[e];
    if (s[i1] - s2 < GAP_TAU) {
      int idx = atomicAdd(nflag, 1);
      worklist[idx] = b;
    }
  }
}

// ---- Phase B1: fp64 g for flagged rows. Latency-bound (~190 blocks, <1
// wave/SIMD, zero TLP): wall time = iters x exposed miss latency. Batch 64
// w1 loads per wait (16 iterations; was 32x32 in r11, 64x16 in r10 at 46us).
__global__ __launch_bounds__(256) void fixup_g_kernel(
    const float* __restrict__ x, const float* __restrict__ w1,
    const float* __restrict__ b1, const int* __restrict__ nflag,
    const int* __restrict__ worklist, double* __restrict__ g64) {
  __shared__ float xs[D_INK];
  int n = *nflag;
  int total = n * 2;  // tiles of 256 cols
  int tid = threadIdx.x;
  for (int t = blockIdx.x; t < total; t += gridDim.x) {
    int w = t >> 1, half = t & 1;
    int row = worklist[w];
    int col = half * 256 + tid;
    ((float4*)xs)[tid] = ((const float4*)(x + (long)row * D_INK))[tid];
    __syncthreads();
    double a[4] = {0.0, 0.0, 0.0, 0.0};
    for (int k = 0; k < D_INK; k += 64) {
      float wv[64];
#pragma unroll
      for (int j = 0; j < 64; ++j) wv[j] = w1[(long)(k + j) * D_H + col];
#pragma unroll
      for (int j = 0; j < 64; ++j)
        a[j & 3] = fma((double)xs[k + j], (double)wv[j], a[j & 3]);
    }
    double s = ((a[0] + a[1]) + (a[2] + a[3])) + (double)b1[col];
    g64[(long)w * D_H + col] = 0.5 * s * (1.0 + erf(s * 0.70710678118654752440));
    __syncthreads();  // xs consumed before next tile overwrites
  }
}

// ---- Phase B2: fp64 scores from g64, block per flagged row. Grid 512. ----
__global__ __launch_bounds__(256) void fixup_score_kernel(
    const double* __restrict__ g64, const float* __restrict__ w2,
    const float* __restrict__ b2, const int* __restrict__ nflag,
    const int* __restrict__ worklist, float* __restrict__ scores) {
  __shared__ double p2[256];
  int n = *nflag;
  int tid = threadIdx.x;
  for (int w = blockIdx.x; w < n; w += gridDim.x) {
    int row = worklist[w];
    int e = tid & 7, seg = tid >> 3;  // 32 segments of 16
    double s = 0.0;
#pragma unroll
    for (int q = seg * 16; q < seg * 16 + 16; ++q)
      s += g64[(long)w * D_H + q] * (double)w2[q * N_E + e];
    p2[tid] = s;
    __syncthreads();
    if (tid < N_E) {
      double t = 0.0;
      for (int i = 0; i < 32; ++i) t += p2[i * 8 + tid];
      scores[row * N_E + tid] = (float)(t + (double)b2[tid]);
    }
    __syncthreads();
  }
}

// ---- Phase C: top-2 + softmax + bucket scatter, hierarchical ranks ----
__global__ __launch_bounds__(256) void select_kernel(
    const float* __restrict__ scores, int* __restrict__ counts,
    int* __restrict__ bucket, float* __restrict__ pair_w,
    int* __restrict__ pair_e) {
  __shared__ int lcnt[N_E];
  __shared__ int lbase[N_E];
  int tid = threadIdx.x;
  int b = blockIdx.x * 256 + tid;
  if (tid < N_E) lcnt[tid] = 0;
  __syncthreads();
  float4 sa = *(const float4*)(scores + (long)b * N_E);
  float4 sb = *(const float4*)(scores + (long)b * N_E + 4);
  float s[8] = {sa.x, sa.y, sa.z, sa.w, sb.x, sb.y, sb.z, sb.w};
  int i0 = 0;
#pragma unroll
  for (int e = 1; e < 8; ++e) if (s[e] > s[i0]) i0 = e;
  int i1 = (i0 == 0) ? 1 : 0;
#pragma unroll
  for (int e = 0; e < 8; ++e) if (e != i0 && s[e] > s[i1]) i1 = e;
  float z = expf(s[i1] - s[i0]);  // <= 1
  float inv = 1.0f / (1.0f + z);
  int r0 = atomicAdd(&lcnt[i0], 1);
  int r1 = atomicAdd(&lcnt[i1], 1);
  __syncthreads();
  if (tid < N_E) lbase[tid] = atomicAdd(&counts[tid], lcnt[tid]);
  __syncthreads();
  int p0 = 2 * b, p1 = 2 * b + 1;
  pair_e[p0] = i0; pair_w[p0] = inv;
  pair_e[p1] = i1; pair_w[p1] = z * inv;
  bucket[i0 * B_ROWS + lbase[i0] + r0] = p0;
  bucket[i1 * B_ROWS + lbase[i1] + r1] = p1;
}

// ---- grouped expert GEMM (fp16): h[pair] = x[row] @ We[e], bf16 out ----
// FROZEN round-7/9 form, SINGLE dispatch (r11 lesson: 2-way split = 2
// blocks/CU per half = 95us total vs 71.5 combined). 128^2 tile, 4 waves,
// single buffer, 33KB -> 4 blocks/CU; 3D grid nt fastest (bid%8 = nt ->
// per-XCD 2MB B-set L2-pinned), e/mt balanced.
__global__ __launch_bounds__(256) void expert_gemm_kernel(
    const _Float16* __restrict__ xh, const _Float16* __restrict__ wet,
    const int* __restrict__ counts, const int* __restrict__ bucket,
    __bf16* __restrict__ h) {
  int nt = blockIdx.x, mt = blockIdx.y, e = blockIdx.z;
  int cnt = counts[e];
  if (mt * 128 >= cnt) return;
  __shared__ __align__(16) unsigned short As[128 * 64];
  __shared__ __align__(16) unsigned short Bs[128 * 64];
  __shared__ int dest_s[128];
  int tid = threadIdx.x, lane = tid & 63, wave = tid >> 6;
  int wm = wave >> 1, wn = wave & 1;
  int n0 = nt * 128;
  if (tid < 128) {
    int idx = mt * 128 + tid;
    dest_s[tid] = (idx < cnt) ? bucket[e * B_ROWS + idx] : 0;
  }
  __syncthreads();
  const char* xb = (const char*)xh;
  const char* wb = (const char*)wet + (long)e * (D_INK * OUT_D * 2);
  const char* aptr[4];
  const char* bptr[4];
#pragma unroll
  for (int i = 0; i < 4; ++i) {
    int f = i * 256 + tid;
    int rowt = f >> 3, slot = f & 7;
    int seg = slot ^ (rowt & 7);  // source-address swizzle
    int rowid = dest_s[rowt] >> 1;
    aptr[i] = xb + (long)rowid * (D_INK * 2) + seg * 16;
    bptr[i] = wb + (long)(n0 + rowt) * (D_INK * 2) + seg * 16;
  }
  f32x4 acc[4][4];
#pragma unroll
  for (int mi = 0; mi < 4; ++mi)
#pragma unroll
    for (int ni = 0; ni < 4; ++ni) acc[mi][ni] = (f32x4){0.f, 0.f, 0.f, 0.f};

  int cl = lane & 15, quad = lane >> 4;
  for (int k0 = 0; k0 < D_INK; k0 += 64) {
    stage8(aptr, bptr, (long)k0 * 2, (char*)As, (char*)Bs, wave);
    __syncthreads();  // drains DMA (vmcnt) -> tile visible
    tile_compute((const char*)As, (const char*)Bs, wm, wn, cl, quad, acc);
    __syncthreads();  // tile consumed before next DMA overwrites
  }
#pragma unroll
  for (int mi = 0; mi < 4; ++mi)
#pragma unroll
    for (int r = 0; r < 4; ++r) {
      int row128 = wm * 64 + mi * 16 + quad * 4 + r;
      if (mt * 128 + row128 < cnt) {
        long dest = dest_s[row128];
        __bf16* hp = h + dest * OUT_D + n0 + wn * 64 + cl;
#pragma unroll
        for (int ni = 0; ni < 4; ++ni)
          hp[ni * 16] = (__bf16)clamp_diag(acc[mi][ni][r]);
      }
    }
}

// ---- LN(+be) -> GELU -> weighted combine -> fp32 out (block per row) ----
__global__ __launch_bounds__(256) void ln_combine_kernel(
    const __bf16* __restrict__ h, const float* __restrict__ pair_w,
    const int* __restrict__ pair_e, const float* __restrict__ be,
    const float* __restrict__ ln_g, const float* __restrict__ ln_b,
    float* __restrict__ out) {
  int b = blockIdx.x, tid = threadIdx.x;
  int lane = tid & 63, wave = tid >> 6;
  int c0 = tid * 4;
  __shared__ float red[4][4];
  float hv[2][4];
  float stats[4];
  int ei[2]; float wi[2];
#pragma unroll
  for (int k = 0; k < 2; ++k) {
    int p = 2 * b + k;
    ei[k] = pair_e[p]; wi[k] = pair_w[p];
    const unsigned short* hp = (const unsigned short*)(h + (long)p * OUT_D) + c0;
    ushort4 raw = *(const ushort4*)hp;
    float4 bev = *(const float4*)(be + ei[k] * OUT_D + c0);
    float v0 = __uint_as_float((unsigned)raw.x << 16) + bev.x;
    float v1 = __uint_as_float((unsigned)raw.y << 16) + bev.y;
    float v2 = __uint_as_float((unsigned)raw.z << 16) + bev.z;
    float v3 = __uint_as_float((unsigned)raw.w << 16) + bev.w;
    hv[k][0] = v0; hv[k][1] = v1; hv[k][2] = v2; hv[k][3] = v3;
    stats[2 * k] = v0 + v1 + v2 + v3;
    stats[2 * k + 1] = v0 * v0 + v1 * v1 + v2 * v2 + v3 * v3;
  }
#pragma unroll
  for (int off = 32; off >= 1; off >>= 1)
#pragma unroll
    for (int i = 0; i < 4; ++i) stats[i] += __shfl_xor(stats[i], off, 64);
  if (lane == 0) {
#pragma unroll
    for (int i = 0; i < 4; ++i) red[wave][i] = stats[i];
  }
  __syncthreads();
  float tot[4] = {0.f, 0.f, 0.f, 0.f};
#pragma unroll
  for (int w = 0; w < 4; ++w)
#pragma unroll
    for (int i = 0; i < 4; ++i) tot[i] += red[w][i];
  float outv[4] = {0.f, 0.f, 0.f, 0.f};
#pragma unroll
  for (int k = 0; k < 2; ++k) {
    float mean = tot[2 * k] * (1.0f / OUT_D);
    float var = tot[2 * k + 1] * (1.0f / OUT_D) - mean * mean;
    float rstd = rsqrtf(fmaxf(var, 0.f) + LN_EPS);
    float4 gp = *(const float4*)(ln_g + ei[k] * OUT_D + c0);
    float4 bp = *(const float4*)(ln_b + ei[k] * OUT_D + c0);
    float t0 = (hv[k][0] - mean) * rstd * gp.x + bp.x;
    float t1 = (hv[k][1] - mean) * rstd * gp.y + bp.y;
    float t2 = (hv[k][2] - mean) * rstd * gp.z + bp.z;
    float t3 = (hv[k][3] - mean) * rstd * gp.w + bp.w;
    outv[0] += wi[k] * gelu_exact(t0);
    outv[1] += wi[k] * gelu_exact(t1);
    outv[2] += wi[k] * gelu_exact(t2);
    outv[3] += wi[k] * gelu_exact(t3);
  }
  float4 o; o.x = outv[0]; o.y = outv[1]; o.z = outv[2]; o.w = outv[3];
  *(float4*)(out + (long)b * OUT_D + c0) = o;
}

extern "C" void kernel_launch(void* const* d_in, const int* in_sizes, int n_in,
                              void* d_out, int out_size, void* d_ws, size_t ws_size,
                              hipStream_t stream) {
  const float* x       = (const float*)d_in[0];
  const float* gate_w1 = (const float*)d_in[1];
  const float* gate_b1 = (const float*)d_in[2];
  const float* gate_w2 = (const float*)d_in[3];
  const float* gate_b2 = (const float*)d_in[4];
  const float* We      = (const float*)d_in[5];
  const float* be      = (const float*)d_in[6];
  const float* ln_g    = (const float*)d_in[7];
  const float* ln_b    = (const float*)d_in[8];
  float* out = (float*)d_out;  // reference output dtype is float32

  char* ws = (char*)d_ws;
  size_t off = 0;
  _Float16* x16h = (_Float16*)(ws + off); off += (size_t)B_ROWS * D_INK * 2;   // 16 MB
  _Float16* w1th = (_Float16*)(ws + off); off += (size_t)D_H * D_INK * 2;      // 1 MB
  _Float16* wet  = (_Float16*)(ws + off); off += (size_t)N_E * D_INK * OUT_D * 2; // 16 MB
  float* g       = (float*)(ws + off); off += (size_t)B_ROWS * D_H * 4;        // 16 MB
  float* scores  = (float*)(ws + off); off += (size_t)B_ROWS * N_E * 4;        // 256 KB
  int* counts    = (int*)(ws + off);   off += 64;  // counts[8] + nflag
  int* nflag     = counts + 8;
  int* worklist  = (int*)(ws + off);   off += (size_t)B_ROWS * 4;              // 32 KB
  int* bucket    = (int*)(ws + off);   off += (size_t)N_E * B_ROWS * 4;        // 256 KB
  float* pair_w  = (float*)(ws + off); off += (size_t)2 * B_ROWS * 4;
  int* pair_e    = (int*)(ws + off);   off += (size_t)2 * B_ROWS * 4;
  __bf16* h      = (__bf16*)(ws + off); off += (size_t)2 * B_ROWS * OUT_D * 2; // 32 MB
  // g64 aliases h: used only between fixup_g and fixup_score, both of which
  // complete before expert_gemm writes h. Worst case n=8192 -> 32 MB = |h|.
  double* g64    = (double*)h;

  // 8 dispatches: prep fuses convert + 2 transposes + counts-zero.
  prep_kernel<<<8192 + 512 + 8192, 256, 0, stream>>>(
      x, (f16x4v*)x16h, gate_w1, w1th, We, wet, counts);
  gate_gemm_kernel<<<dim3(D_H / 64, B_ROWS / 64), 256, 0, stream>>>(
      x16h, w1th, gate_b1, g);
  score_kernel<<<B_ROWS / 4, 256, 0, stream>>>(
      g, gate_w2, gate_b2, scores, nflag, worklist);
  fixup_g_kernel<<<2048, 256, 0, stream>>>(
      x, gate_w1, gate_b1, nflag, worklist, g64);
  fixup_score_kernel<<<512, 256, 0, stream>>>(
      g64, gate_w2, gate_b2, nflag, worklist, scores);
  select_kernel<<<B_ROWS / 256, 256, 0, stream>>>(
      scores, counts, bucket, pair_w, pair_e);
  expert_gemm_kernel<<<dim3(OUT_D / 128, B_ROWS / 128, N_E), 256, 0, stream>>>(
      x16h, wet, counts, bucket, h);
  ln_combine_kernel<<<B_ROWS, 256, 0, stream>>>(
      h, pair_w, pair_e, be, ln_g, ln_b, out);
}

// Round 13
// 283.747 us; speedup vs baseline: 1.0247x; 1.0247x over previous
//
#include <hip/hip_runtime.h>
#include <hip/hip_bf16.h>
#include <math.h>

#define B_ROWS 8192
#define D_INK  1024
#define D_H    512
#define N_E    8
#define OUT_D  1024
#define LN_EPS 1e-5f
#define GAP_TAU 3e-3f

typedef _Float16 f16x8 __attribute__((ext_vector_type(8)));
typedef _Float16 f16x4v __attribute__((ext_vector_type(4)));
typedef float    f32x4  __attribute__((ext_vector_type(4)));

#define GLOBAL_AS __attribute__((address_space(1)))
#define LDS_AS    __attribute__((address_space(3)))

// Async 16B global->LDS DMA. LDS dest is wave-uniform base + lane*16.
__device__ __forceinline__ void async16(const void* gptr, void* lptr) {
  __builtin_amdgcn_global_load_lds((const GLOBAL_AS unsigned int*)gptr,
                                   (LDS_AS unsigned int*)lptr, 16, 0, 0);
}

__device__ __forceinline__ float gelu_exact(float x) {
  return 0.5f * x * (1.0f + erff(x * 0.707106781186547524f));
}
__device__ __forceinline__ float clamp_diag(float v) {
  return fminf(fmaxf(v, -1e15f), 1e15f);
}

// ---- fused prep: convert x -> fp16, transpose w1 and We -> fp16, zero
// counts. One kernel instead of 4 dispatch nodes. Roles by blockIdx range.
__global__ __launch_bounds__(256) void prep_kernel(
    const float* __restrict__ x, f16x4v* __restrict__ x16h4,
    const float* __restrict__ gate_w1, _Float16* __restrict__ w1th,
    const float* __restrict__ We, _Float16* __restrict__ wet,
    int* __restrict__ counts) {
  __shared__ float tile[32][33];
  int bid = blockIdx.x, tid = threadIdx.x;
  if (bid < 8192) {  // convert role: 8192 blocks cover 8192x1024 / 4
    if (bid == 0 && tid < 16) counts[tid] = 0;  // counts[8] + nflag + pad
    int i = bid * 256 + tid;
    float4 v = ((const float4*)x)[i];
    f16x4v h;
    h[0] = (_Float16)v.x; h[1] = (_Float16)v.y;
    h[2] = (_Float16)v.z; h[3] = (_Float16)v.w;
    x16h4[i] = h;
    return;
  }
  const float* src; _Float16* dst; int C; long base; int c0, r0;
  if (bid < 8192 + 512) {  // w1 transpose: 16 x 32 tiles
    int b2 = bid - 8192;
    src = gate_w1; dst = w1th; C = D_H; base = 0;
    c0 = (b2 & 15) * 32; r0 = (b2 >> 4) * 32;
  } else {  // We transpose: 32 x 32 x 8 tiles
    int b3 = bid - 8704;
    src = We; dst = wet; C = OUT_D;
    int zx = b3 & 31, zy = (b3 >> 5) & 31, zz = b3 >> 10;
    base = (long)zz * D_INK * OUT_D;
    c0 = zx * 32; r0 = zy * 32;
  }
  int tx = tid & 31, ty = tid >> 5;
#pragma unroll
  for (int i = ty; i < 32; i += 8)
    tile[i][tx] = src[base + (long)(r0 + i) * C + (c0 + tx)];
  __syncthreads();
#pragma unroll
  for (int i = ty; i < 32; i += 8)
    dst[base + (long)(c0 + i) * D_INK + (r0 + tx)] = (_Float16)tile[tx][i];
}

// LDS tile layout (both GEMMs): rows of 64 fp16 = 8 segs of 16B, segment
// index XOR-swizzled by (row&7): data(row,seg) at row*128 + (seg^(row&7))*16.
// Staging fetches global segment slot^(row&7) into LDS slot `slot` so the
// DMA's rigid base+lane*16 mapping lands data swizzled. MFMA reads then are
// 2-way bank-aliased (free, m136) instead of 16-way.
//
// Structure law (rounds 0-4, 10-12): single-buffer 2-barrier K-loop with
// >=4 blocks/CU wins. EVERY <4 blocks/CU variant regressed, including
// dispatch splits (r11: 2 halves at 2 blocks/CU = 95us vs 71.5 merged).
// Grid-mapping law (rounds 7-8): keep the STREAMING operand (B) L2-pinned
// per XCD (nt fastest); let the gathered operand (A) refetch through L3.
// Latency law (rounds 6/10): sparse-grid kernels expose full miss latency
// per dependent batch — batch more loads per wait, BUT keep the unrolled
// register array <=32 (r12: batch-64 wv[64] regressed ~26us — spill).

// Stage one 128x64 A-tile + 128x64 B-tile K-step into the given LDS buffers.
__device__ __forceinline__ void stage8(const char* const (&ap)[4],
                                       const char* const (&bp)[4], long koff,
                                       char* Ab, char* Bb, int wave) {
#pragma unroll
  for (int i = 0; i < 4; ++i) {
    async16(ap[i] + koff, Ab + (i * 256 + wave * 64) * 16);
    async16(bp[i] + koff, Bb + (i * 256 + wave * 64) * 16);
  }
}

// One K-step (BK=64) of 16x16x32 MFMAs from swizzled LDS tiles. 32 MFMA/wave.
__device__ __forceinline__ void tile_compute(const char* Ab, const char* Bb,
                                             int wm, int wn, int cl, int quad,
                                             f32x4 (&acc)[4][4]) {
#pragma unroll
  for (int ks = 0; ks < 2; ++ks) {
    f16x8 ah[4], bh[4];
#pragma unroll
    for (int mi = 0; mi < 4; ++mi) {
      int row = wm * 64 + mi * 16 + cl;
      ah[mi] = *(const f16x8*)(Ab + row * 128 + (((ks * 4 + quad) ^ (cl & 7)) * 16));
    }
#pragma unroll
    for (int ni = 0; ni < 4; ++ni) {
      int row = wn * 64 + ni * 16 + cl;
      bh[ni] = *(const f16x8*)(Bb + row * 128 + (((ks * 4 + quad) ^ (cl & 7)) * 16));
    }
#pragma unroll
    for (int mi = 0; mi < 4; ++mi)
#pragma unroll
      for (int ni = 0; ni < 4; ++ni)
        acc[mi][ni] = __builtin_amdgcn_mfma_f32_16x16x32_f16(ah[mi], bh[ni], acc[mi][ni], 0, 0, 0);
  }
}

// ---- gate GEMM, fp16 1-term: g = gelu(x@W1 + b1) fp32 out ----
// 64x64 tile -> 1024 blocks = 4 blocks/CU; nt fastest (B-slice L2-pinned).
__global__ __launch_bounds__(256) void gate_gemm_kernel(
    const _Float16* __restrict__ xh, const _Float16* __restrict__ wh,
    const float* __restrict__ b1, float* __restrict__ g) {
  __shared__ __align__(16) unsigned short Ah[64 * 64];
  __shared__ __align__(16) unsigned short Bh[64 * 64];
  int tid = threadIdx.x, lane = tid & 63, wave = tid >> 6;
  int wm = wave >> 1, wn = wave & 1;
  int n0 = blockIdx.x * 64, m0 = blockIdx.y * 64;

  const char* pah[2]; const char* pbh[2];
#pragma unroll
  for (int i = 0; i < 2; ++i) {
    int f = i * 256 + tid;
    int rowt = f >> 3, slot = f & 7;
    int seg = slot ^ (rowt & 7);  // source-address swizzle
    pah[i] = (const char*)xh + (long)(m0 + rowt) * (D_INK * 2) + seg * 16;
    pbh[i] = (const char*)wh + (long)(n0 + rowt) * (D_INK * 2) + seg * 16;
  }
  f32x4 acc[2][2];
#pragma unroll
  for (int mi = 0; mi < 2; ++mi)
#pragma unroll
    for (int ni = 0; ni < 2; ++ni) acc[mi][ni] = (f32x4){0.f, 0.f, 0.f, 0.f};

  int cl = lane & 15, quad = lane >> 4;
  for (int k0 = 0; k0 < D_INK; k0 += 64) {
    long koff = (long)k0 * 2;
#pragma unroll
    for (int i = 0; i < 2; ++i) {
      async16(pah[i] + koff, (char*)Ah + (i * 256 + wave * 64) * 16);
      async16(pbh[i] + koff, (char*)Bh + (i * 256 + wave * 64) * 16);
    }
    __syncthreads();  // drains DMA (vmcnt) -> tile visible
#pragma unroll
    for (int ks = 0; ks < 2; ++ks) {
      f16x8 ah[2], bh[2];
#pragma unroll
      for (int mi = 0; mi < 2; ++mi) {
        int row = wm * 32 + mi * 16 + cl;
        ah[mi] = *(const f16x8*)((const char*)Ah + row * 128 +
                                 (((ks * 4 + quad) ^ (cl & 7)) * 16));
      }
#pragma unroll
      for (int ni = 0; ni < 2; ++ni) {
        int row = wn * 32 + ni * 16 + cl;
        bh[ni] = *(const f16x8*)((const char*)Bh + row * 128 +
                                 (((ks * 4 + quad) ^ (cl & 7)) * 16));
      }
#pragma unroll
      for (int mi = 0; mi < 2; ++mi)
#pragma unroll
        for (int ni = 0; ni < 2; ++ni)
          acc[mi][ni] = __builtin_amdgcn_mfma_f32_16x16x32_f16(ah[mi], bh[ni], acc[mi][ni], 0, 0, 0);
    }
    __syncthreads();  // tile consumed before next DMA overwrites
  }
#pragma unroll
  for (int mi = 0; mi < 2; ++mi)
#pragma unroll
    for (int r = 0; r < 4; ++r) {
      int row = m0 + wm * 32 + mi * 16 + quad * 4 + r;
#pragma unroll
      for (int ni = 0; ni < 2; ++ni) {
        int col = n0 + wn * 32 + ni * 16 + cl;
        float v = clamp_diag(acc[mi][ni][r] + b1[col]);
        g[(long)row * D_H + col] = gelu_exact(v);
      }
    }
}

// ---- Phase A: scores (fp32) + flag close 2nd/3rd gaps. One wave per row.
// w2 slice per lane (256B contiguous) preloaded as 16 float4s; FMA order
// identical to original (bitwise-same fp32 result).
__global__ __launch_bounds__(256) void score_kernel(
    const float* __restrict__ g, const float* __restrict__ w2,
    const float* __restrict__ b2, float* __restrict__ scores,
    int* __restrict__ nflag, int* __restrict__ worklist) {
  int tid = threadIdx.x, lane = tid & 63, wave = tid >> 6;
  int b = blockIdx.x * 4 + wave;
  const float* grow = g + (long)b * D_H + lane * 8;
  float4 g0 = *(const float4*)grow;
  float4 g1 = *(const float4*)(grow + 4);
  float gv[8] = {g0.x, g0.y, g0.z, g0.w, g1.x, g1.y, g1.z, g1.w};
  float4 wv4[16];
  const float4* wq = (const float4*)(w2 + lane * 64);
#pragma unroll
  for (int jj = 0; jj < 16; ++jj) wv4[jj] = wq[jj];
  const float* wv = (const float*)wv4;  // wv[j*8+e] = w2[(lane*8+j)*8+e]
  float acc[8];
#pragma unroll
  for (int e = 0; e < 8; ++e) acc[e] = 0.f;
#pragma unroll
  for (int j = 0; j < 8; ++j)
#pragma unroll
    for (int e = 0; e < 8; ++e) acc[e] += gv[j] * wv[j * 8 + e];
#pragma unroll
  for (int off = 32; off >= 1; off >>= 1)
#pragma unroll
    for (int e = 0; e < 8; ++e) acc[e] += __shfl_xor(acc[e], off, 64);
  if (lane == 0) {
    float s[8];
#pragma unroll
    for (int e = 0; e < 8; ++e) { s[e] = acc[e] + b2[e]; scores[b * N_E + e] = s[e]; }
    int i0 = 0;
#pragma unroll
    for (int e = 1; e < 8; ++e) if (s[e] > s[i0]) i0 = e;
    int i1 = (i0 == 0) ? 1 : 0;
#pragma unroll
    for (int e = 0; e < 8; ++e) if (e != i0 && s[e] > s[i1]) i1 = e;
    float s2 = -3e38f;
#pragma unroll
    for (int e = 0; e < 8; ++e) if (e != i0 && e != i1 && s[e] > s2) s2 = s[e];
    if (s[i1] - s2 < GAP_TAU) {
      int idx = atomicAdd(nflag, 1);
      worklist[idx] = b;
    }
  }
}

// ---- Phase B1: fp64 g for flagged rows. Latency-bound (~190 blocks, <1
// wave/SIMD, zero TLP). Batch 32 w1 loads per wait — r11-proven sweet spot
// (batch 16 = 46us r10; batch 64 regressed ~26us in r12: spill).
__global__ __launch_bounds__(256) void fixup_g_kernel(
    const float* __restrict__ x, const float* __restrict__ w1,
    const float* __restrict__ b1, const int* __restrict__ nflag,
    const int* __restrict__ worklist, double* __restrict__ g64) {
  __shared__ float xs[D_INK];
  int n = *nflag;
  int total = n * 2;  // tiles of 256 cols
  int tid = threadIdx.x;
  for (int t = blockIdx.x; t < total; t += gridDim.x) {
    int w = t >> 1, half = t & 1;
    int row = worklist[w];
    int col = half * 256 + tid;
    ((float4*)xs)[tid] = ((const float4*)(x + (long)row * D_INK))[tid];
    __syncthreads();
    double a[4] = {0.0, 0.0, 0.0, 0.0};
    for (int k = 0; k < D_INK; k += 32) {
      float wv[32];
#pragma unroll
      for (int j = 0; j < 32; ++j) wv[j] = w1[(long)(k + j) * D_H + col];
#pragma unroll
      for (int j = 0; j < 32; ++j)
        a[j & 3] = fma((double)xs[k + j], (double)wv[j], a[j & 3]);
    }
    double s = ((a[0] + a[1]) + (a[2] + a[3])) + (double)b1[col];
    g64[(long)w * D_H + col] = 0.5 * s * (1.0 + erf(s * 0.70710678118654752440));
    __syncthreads();  // xs consumed before next tile overwrites
  }
}

// ---- Phase B2: fp64 scores from g64, block per flagged row. Grid 512. ----
__global__ __launch_bounds__(256) void fixup_score_kernel(
    const double* __restrict__ g64, const float* __restrict__ w2,
    const float* __restrict__ b2, const int* __restrict__ nflag,
    const int* __restrict__ worklist, float* __restrict__ scores) {
  __shared__ double p2[256];
  int n = *nflag;
  int tid = threadIdx.x;
  for (int w = blockIdx.x; w < n; w += gridDim.x) {
    int row = worklist[w];
    int e = tid & 7, seg = tid >> 3;  // 32 segments of 16
    double s = 0.0;
#pragma unroll
    for (int q = seg * 16; q < seg * 16 + 16; ++q)
      s += g64[(long)w * D_H + q] * (double)w2[q * N_E + e];
    p2[tid] = s;
    __syncthreads();
    if (tid < N_E) {
      double t = 0.0;
      for (int i = 0; i < 32; ++i) t += p2[i * 8 + tid];
      scores[row * N_E + tid] = (float)(t + (double)b2[tid]);
    }
    __syncthreads();
  }
}

// ---- Phase C: top-2 + softmax + bucket scatter, hierarchical ranks ----
__global__ __launch_bounds__(256) void select_kernel(
    const float* __restrict__ scores, int* __restrict__ counts,
    int* __restrict__ bucket, float* __restrict__ pair_w,
    int* __restrict__ pair_e) {
  __shared__ int lcnt[N_E];
  __shared__ int lbase[N_E];
  int tid = threadIdx.x;
  int b = blockIdx.x * 256 + tid;
  if (tid < N_E) lcnt[tid] = 0;
  __syncthreads();
  float4 sa = *(const float4*)(scores + (long)b * N_E);
  float4 sb = *(const float4*)(scores + (long)b * N_E + 4);
  float s[8] = {sa.x, sa.y, sa.z, sa.w, sb.x, sb.y, sb.z, sb.w};
  int i0 = 0;
#pragma unroll
  for (int e = 1; e < 8; ++e) if (s[e] > s[i0]) i0 = e;
  int i1 = (i0 == 0) ? 1 : 0;
#pragma unroll
  for (int e = 0; e < 8; ++e) if (e != i0 && s[e] > s[i1]) i1 = e;
  float z = expf(s[i1] - s[i0]);  // <= 1
  float inv = 1.0f / (1.0f + z);
  int r0 = atomicAdd(&lcnt[i0], 1);
  int r1 = atomicAdd(&lcnt[i1], 1);
  __syncthreads();
  if (tid < N_E) lbase[tid] = atomicAdd(&counts[tid], lcnt[tid]);
  __syncthreads();
  int p0 = 2 * b, p1 = 2 * b + 1;
  pair_e[p0] = i0; pair_w[p0] = inv;
  pair_e[p1] = i1; pair_w[p1] = z * inv;
  bucket[i0 * B_ROWS + lbase[i0] + r0] = p0;
  bucket[i1 * B_ROWS + lbase[i1] + r1] = p1;
}

// ---- grouped expert GEMM (fp16): h[pair] = x[row] @ We[e], bf16 out ----
// FROZEN round-7/9/12 form, SINGLE dispatch: 128^2 tile, 4 waves, single
// buffer, 33KB LDS -> 4 blocks/CU; 3D grid nt fastest (bid%8 = nt ->
// per-XCD 2MB B-set L2-pinned), e/mt balanced. Proven 71.5us fingerprint:
// MfmaUtil ~19.5, FETCH ~117MB, hbm ~2.15 TB/s.
__global__ __launch_bounds__(256) void expert_gemm_kernel(
    const _Float16* __restrict__ xh, const _Float16* __restrict__ wet,
    const int* __restrict__ counts, const int* __restrict__ bucket,
    __bf16* __restrict__ h) {
  int nt = blockIdx.x, mt = blockIdx.y, e = blockIdx.z;
  int cnt = counts[e];
  if (mt * 128 >= cnt) return;
  __shared__ __align__(16) unsigned short As[128 * 64];
  __shared__ __align__(16) unsigned short Bs[128 * 64];
  __shared__ int dest_s[128];
  int tid = threadIdx.x, lane = tid & 63, wave = tid >> 6;
  int wm = wave >> 1, wn = wave & 1;
  int n0 = nt * 128;
  if (tid < 128) {
    int idx = mt * 128 + tid;
    dest_s[tid] = (idx < cnt) ? bucket[e * B_ROWS + idx] : 0;
  }
  __syncthreads();
  const char* xb = (const char*)xh;
  const char* wb = (const char*)wet + (long)e * (D_INK * OUT_D * 2);
  const char* aptr[4];
  const char* bptr[4];
#pragma unroll
  for (int i = 0; i < 4; ++i) {
    int f = i * 256 + tid;
    int rowt = f >> 3, slot = f & 7;
    int seg = slot ^ (rowt & 7);  // source-address swizzle
    int rowid = dest_s[rowt] >> 1;
    aptr[i] = xb + (long)rowid * (D_INK * 2) + seg * 16;
    bptr[i] = wb + (long)(n0 + rowt) * (D_INK * 2) + seg * 16;
  }
  f32x4 acc[4][4];
#pragma unroll
  for (int mi = 0; mi < 4; ++mi)
#pragma unroll
    for (int ni = 0; ni < 4; ++ni) acc[mi][ni] = (f32x4){0.f, 0.f, 0.f, 0.f};

  int cl = lane & 15, quad = lane >> 4;
  for (int k0 = 0; k0 < D_INK; k0 += 64) {
    stage8(aptr, bptr, (long)k0 * 2, (char*)As, (char*)Bs, wave);
    __syncthreads();  // drains DMA (vmcnt) -> tile visible
    tile_compute((const char*)As, (const char*)Bs, wm, wn, cl, quad, acc);
    __syncthreads();  // tile consumed before next DMA overwrites
  }
#pragma unroll
  for (int mi = 0; mi < 4; ++mi)
#pragma unroll
    for (int r = 0; r < 4; ++r) {
      int row128 = wm * 64 + mi * 16 + quad * 4 + r;
      if (mt * 128 + row128 < cnt) {
        long dest = dest_s[row128];
        __bf16* hp = h + dest * OUT_D + n0 + wn * 64 + cl;
#pragma unroll
        for (int ni = 0; ni < 4; ++ni)
          hp[ni * 16] = (__bf16)clamp_diag(acc[mi][ni][r]);
      }
    }
}

// ---- LN(+be) -> GELU -> weighted combine -> fp32 out (block per row) ----
__global__ __launch_bounds__(256) void ln_combine_kernel(
    const __bf16* __restrict__ h, const float* __restrict__ pair_w,
    const int* __restrict__ pair_e, const float* __restrict__ be,
    const float* __restrict__ ln_g, const float* __restrict__ ln_b,
    float* __restrict__ out) {
  int b = blockIdx.x, tid = threadIdx.x;
  int lane = tid & 63, wave = tid >> 6;
  int c0 = tid * 4;
  __shared__ float red[4][4];
  float hv[2][4];
  float stats[4];
  int ei[2]; float wi[2];
#pragma unroll
  for (int k = 0; k < 2; ++k) {
    int p = 2 * b + k;
    ei[k] = pair_e[p]; wi[k] = pair_w[p];
    const unsigned short* hp = (const unsigned short*)(h + (long)p * OUT_D) + c0;
    ushort4 raw = *(const ushort4*)hp;
    float4 bev = *(const float4*)(be + ei[k] * OUT_D + c0);
    float v0 = __uint_as_float((unsigned)raw.x << 16) + bev.x;
    float v1 = __uint_as_float((unsigned)raw.y << 16) + bev.y;
    float v2 = __uint_as_float((unsigned)raw.z << 16) + bev.z;
    float v3 = __uint_as_float((unsigned)raw.w << 16) + bev.w;
    hv[k][0] = v0; hv[k][1] = v1; hv[k][2] = v2; hv[k][3] = v3;
    stats[2 * k] = v0 + v1 + v2 + v3;
    stats[2 * k + 1] = v0 * v0 + v1 * v1 + v2 * v2 + v3 * v3;
  }
#pragma unroll
  for (int off = 32; off >= 1; off >>= 1)
#pragma unroll
    for (int i = 0; i < 4; ++i) stats[i] += __shfl_xor(stats[i], off, 64);
  if (lane == 0) {
#pragma unroll
    for (int i = 0; i < 4; ++i) red[wave][i] = stats[i];
  }
  __syncthreads();
  float tot[4] = {0.f, 0.f, 0.f, 0.f};
#pragma unroll
  for (int w = 0; w < 4; ++w)
#pragma unroll
    for (int i = 0; i < 4; ++i) tot[i] += red[w][i];
  float outv[4] = {0.f, 0.f, 0.f, 0.f};
#pragma unroll
  for (int k = 0; k < 2; ++k) {
    float mean = tot[2 * k] * (1.0f / OUT_D);
    float var = tot[2 * k + 1] * (1.0f / OUT_D) - mean * mean;
    float rstd = rsqrtf(fmaxf(var, 0.f) + LN_EPS);
    float4 gp = *(const float4*)(ln_g + ei[k] * OUT_D + c0);
    float4 bp = *(const float4*)(ln_b + ei[k] * OUT_D + c0);
    float t0 = (hv[k][0] - mean) * rstd * gp.x + bp.x;
    float t1 = (hv[k][1] - mean) * rstd * gp.y + bp.y;
    float t2 = (hv[k][2] - mean) * rstd * gp.z + bp.z;
    float t3 = (hv[k][3] - mean) * rstd * gp.w + bp.w;
    outv[0] += wi[k] * gelu_exact(t0);
    outv[1] += wi[k] * gelu_exact(t1);
    outv[2] += wi[k] * gelu_exact(t2);
    outv[3] += wi[k] * gelu_exact(t3);
  }
  float4 o; o.x = outv[0]; o.y = outv[1]; o.z = outv[2]; o.w = outv[3];
  *(float4*)(out + (long)b * OUT_D + c0) = o;
}

extern "C" void kernel_launch(void* const* d_in, const int* in_sizes, int n_in,
                              void* d_out, int out_size, void* d_ws, size_t ws_size,
                              hipStream_t stream) {
  const float* x       = (const float*)d_in[0];
  const float* gate_w1 = (const float*)d_in[1];
  const float* gate_b1 = (const float*)d_in[2];
  const float* gate_w2 = (const float*)d_in[3];
  const float* gate_b2 = (const float*)d_in[4];
  const float* We      = (const float*)d_in[5];
  const float* be      = (const float*)d_in[6];
  const float* ln_g    = (const float*)d_in[7];
  const float* ln_b    = (const float*)d_in[8];
  float* out = (float*)d_out;  // reference output dtype is float32

  char* ws = (char*)d_ws;
  size_t off = 0;
  _Float16* x16h = (_Float16*)(ws + off); off += (size_t)B_ROWS * D_INK * 2;   // 16 MB
  _Float16* w1th = (_Float16*)(ws + off); off += (size_t)D_H * D_INK * 2;      // 1 MB
  _Float16* wet  = (_Float16*)(ws + off); off += (size_t)N_E * D_INK * OUT_D * 2; // 16 MB
  float* g       = (float*)(ws + off); off += (size_t)B_ROWS * D_H * 4;        // 16 MB
  float* scores  = (float*)(ws + off); off += (size_t)B_ROWS * N_E * 4;        // 256 KB
  int* counts    = (int*)(ws + off);   off += 64;  // counts[8] + nflag
  int* nflag     = counts + 8;
  int* worklist  = (int*)(ws + off);   off += (size_t)B_ROWS * 4;              // 32 KB
  int* bucket    = (int*)(ws + off);   off += (size_t)N_E * B_ROWS * 4;        // 256 KB
  float* pair_w  = (float*)(ws + off); off += (size_t)2 * B_ROWS * 4;
  int* pair_e    = (int*)(ws + off);   off += (size_t)2 * B_ROWS * 4;
  __bf16* h      = (__bf16*)(ws + off); off += (size_t)2 * B_ROWS * OUT_D * 2; // 32 MB
  // g64 aliases h: used only between fixup_g and fixup_score, both of which
  // complete before expert_gemm writes h. Worst case n=8192 -> 32 MB = |h|.
  double* g64    = (double*)h;

  // 8 dispatches: prep fuses convert + 2 transposes + counts-zero.
  prep_kernel<<<8192 + 512 + 8192, 256, 0, stream>>>(
      x, (f16x4v*)x16h, gate_w1, w1th, We, wet, counts);
  gate_gemm_kernel<<<dim3(D_H / 64, B_ROWS / 64), 256, 0, stream>>>(
      x16h, w1th, gate_b1, g);
  score_kernel<<<B_ROWS / 4, 256, 0, stream>>>(
      g, gate_w2, gate_b2, scores, nflag, worklist);
  fixup_g_kernel<<<2048, 256, 0, stream>>>(
      x, gate_w1, gate_b1, nflag, worklist, g64);
  fixup_score_kernel<<<512, 256, 0, stream>>>(
      g64, gate_w2, gate_b2, nflag, worklist, scores);
  select_kernel<<<B_ROWS / 256, 256, 0, stream>>>(
      scores, counts, bucket, pair_w, pair_e);
  expert_gemm_kernel<<<dim3(OUT_D / 128, B_ROWS / 128, N_E), 256, 0, stream>>>(
      x16h, wet, counts, bucket, h);
  ln_combine_kernel<<<B_ROWS, 256, 0, stream>>>(
      h, pair_w, pair_e, be, ln_g, ln_b, out);
}